// Round 13
// baseline (138.485 us; speedup 1.0000x reference)
//
#include <hip/hip_runtime.h>
#include <hip/hip_bf16.h>
#include <stdint.h>

#define N1 8192
#define N2 16384
#define DIM 256
#define BM 256              // rows per block = 4 waves x 64
#define CS 16               // col-splits
#define COLS (N2 / CS)      // 1024 cols per block
#define TC 32               // cols per tile (ct=2)
#define NT (COLS / TC)      // 32 tiles per block
#define NPART CS

typedef short v8s  __attribute__((ext_vector_type(8)));   // 8 x bf16 bits
typedef float f32x4 __attribute__((ext_vector_type(4)));

#define GLD16(g, l)                                                                         \
  __builtin_amdgcn_global_load_lds((const __attribute__((address_space(1))) uint32_t*)(g),  \
                                   (__attribute__((address_space(3))) uint32_t*)(l), 16, 0, 0)

__device__ __forceinline__ void top3_insert(float v, float& t0, float& t1, float& t2) {
    float nt1 = __builtin_amdgcn_fmed3f(v, t0, t1);
    float nt2 = __builtin_amdgcn_fmed3f(v, t1, t2);
    t0 = fmaxf(t0, v);
    t1 = nt1;
    t2 = nt2;
}

// 16 lanes per row, 4 rows per wave, 16 rows per block. Each lane: 4 x float4
// loads in flight (ILP), 4-step width-16 shuffle reduce, 4 x uint2 stores.
__global__ __launch_bounds__(256) void normalize_kernel(
        const float* __restrict__ inA, const float* __restrict__ inB,
        __hip_bfloat16* __restrict__ outA, __hip_bfloat16* __restrict__ outB) {
    const int wave = threadIdx.x >> 6;
    const int lane = threadIdx.x & 63;
    const int rgrp = lane >> 4;
    const int li   = lane & 15;
    const int gr   = blockIdx.x * 16 + wave * 4 + rgrp;   // 0..24575
    const float* in;
    __hip_bfloat16* out;
    int row;
    if (gr < N1) { in = inA; out = outA; row = gr; }
    else         { in = inB; out = outB; row = gr - N1; }
    const float* rp = in + (size_t)row * DIM + li * 4;
    float4 v[4];
    #pragma unroll
    for (int j = 0; j < 4; ++j) v[j] = *(const float4*)(rp + j * 64);
    float s = 0.f;
    #pragma unroll
    for (int j = 0; j < 4; ++j)
        s += v[j].x * v[j].x + v[j].y * v[j].y + v[j].z * v[j].z + v[j].w * v[j].w;
    #pragma unroll
    for (int off = 8; off; off >>= 1) s += __shfl_xor(s, off, 64);
    const float inv = 1.0f / sqrtf(s);
    __hip_bfloat16* wp = out + (size_t)row * DIM + li * 4;
    #pragma unroll
    for (int j = 0; j < 4; ++j) {
        __hip_bfloat16 o[4];
        o[0] = __float2bfloat16(v[j].x * inv);
        o[1] = __float2bfloat16(v[j].y * inv);
        o[2] = __float2bfloat16(v[j].z * inv);
        o[3] = __float2bfloat16(v[j].w * inv);
        *(uint2*)(wp + j * 64) = *(uint2*)o;
    }
}

// A-in-AGPR GEMM+top3, rt=4, FREE-RUNNING single-barrier tiles.
// (Resubmission of R12 — the previous round died on container acquisition,
// not on the kernel; audit found no hang/crash mechanism in the diff vs R11.)
// R11 POST-MORTEM: counters showed 38% MfmaUtil with wall 5512 cyc/tile vs
// ~2600 of pipe demand — the gap is ds_read latency exposed inside the MFMA
// cluster (just-in-time bf reads, 8x ~120cyc lgkm waits/tile) while the 4
// barrier-locked waves stall together.
// THIS ROUND: per tile = {vmcnt(0) gate (gated loads are a full tile old ->
// ~free) ; ONE barrier ; issue stage(t+1 -> OTHER buffer) ; bf reads software-
// pipelined 2 s-steps ahead of their MFMAs ; fold}. No within-tile barriers:
// the only cross-wave hazards are at tile boundaries (stage-1-ahead targets
// the buffer whose readers all passed the boundary barrier; reads consume data
// every wave gated before that same barrier). Waves + the 2 co-resident
// blocks free-run and self-stagger -> LDS bursts spread, MFMA pipe stays fed.
// Structure: block = 4 waves x 64 rows = 256 rows x 1024 cols; TC=32 (ct=2);
// af[4][8] pinned in AGPRs (128), arch VGPR ~120 (bf dbuf 16 + acc 32 + t 48).
// grid 512 = 2 blocks/CU; cs = bid&15 -> XCD-local B slab.
// Swizzle: col c chunk g at phys g^(c&7), folded into the global source.
__global__ __launch_bounds__(256, 2) void gemm_top3_kernel(
        const __hip_bfloat16* __restrict__ A, const __hip_bfloat16* __restrict__ B,
        float* __restrict__ partial) {
    __shared__ char smem[2 * 16384];   // B tile double buffer (static bases)

    const int tid  = threadIdx.x;
    const int wave = tid >> 6;
    const int lane = tid & 63;
    const int lo   = lane & 15;
    const int quad = lane >> 4;
    const int cs   = blockIdx.x & 15;
    const int rb   = blockIdx.x >> 4;
    const int row0 = rb * BM;

    // ---- A fragments pinned in AGPRs:
    // af[rt][s] = A[row0+wave*64+rt*16+lo][s*32+quad*8 .. +7]
    v8s af[4][8];
    {
        const char* arow = (const char*)A + (size_t)(row0 + wave * 64 + lo) * 512 + quad * 16;
        #pragma unroll
        for (int rt = 0; rt < 4; ++rt)
            #pragma unroll
            for (int s = 0; s < 8; ++s) {
                v8s t = *(const v8s*)(arow + rt * 8192 + s * 64);
                asm("" : "=a"(af[rt][s]) : "0"(t));   // pin: lives in AGPRs
            }
    }

    // ---- staging constants: 4 GLD16/thread/tile. For j=0..3:
    // col = j*8 + wave*2 + (lane>>5); phys chunk = lane&31;
    // source logical chunk = (lane&31)^(col&7). LDS dst = j*4096 + wave*1024
    // (+ lane*16 by HW) == col*512 + phys*16 exactly. ----
    const char* Bb = (const char*)B + (size_t)cs * COLS * 512;
    int gsrc[4];
    #pragma unroll
    for (int j = 0; j < 4; ++j) {
        const int col = j * 8 + wave * 2 + (lane >> 5);
        gsrc[j] = col * 512 + (((lane & 31) ^ (col & 7)) << 4);
    }

    // ---- read-side swizzle: phys = (s*4+quad) ^ (col&7); (16+lo)&7 == lo&7 ----
    int swz[8];
    #pragma unroll
    for (int s = 0; s < 8; ++s) swz[s] = (((s * 4 + quad) ^ (lo & 7)) << 4);
    const int bco0 = lo * 512;            // ct=0: col lo
    const int bco1 = (16 + lo) * 512;     // ct=1: col 16+lo

    float t0[16], t1[16], t2[16];
    #pragma unroll
    for (int i = 0; i < 16; ++i) { t0[i] = -1e30f; t1[i] = -1e30f; t2[i] = -1e30f; }

    // ---- prologue: stage tile 0 into buf0 (its latency is the one exposed
    // vmcnt(0) at the first tile; every later gate waits on tile-old loads) ----
    #pragma unroll
    for (int j = 0; j < 4; ++j)
        GLD16(Bb + gsrc[j], smem + j * 4096 + wave * 1024);

    // read both ct fragments of s-step S from static buffer base BOFF
    #define RD(dst, S, BOFF)                                                   \
        do {                                                                   \
            (dst)[0] = *(const v8s*)(smem + (BOFF) + bco0 + swz[S]);           \
            (dst)[1] = *(const v8s*)(smem + (BOFF) + bco1 + swz[S]);           \
        } while (0)

    // one tile, single barrier, reads pipelined 2 s-steps ahead of use
    #define DO_TILE(BOFF, OTHER, t)                                            \
    {                                                                          \
        asm volatile("s_waitcnt vmcnt(0)" ::: "memory");                       \
        __builtin_amdgcn_s_barrier();                                          \
        if ((t) + 1 < NT) {                                                    \
            const char* src = Bb + (size_t)((t) + 1) * 16384;                  \
            _Pragma("unroll")                                                  \
            for (int j = 0; j < 4; ++j)                                        \
                GLD16(src + gsrc[j], smem + (OTHER) + j * 4096 + wave * 1024); \
        }                                                                      \
        f32x4 acc[4][2];                                                       \
        _Pragma("unroll")                                                      \
        for (int rt = 0; rt < 4; ++rt) {                                       \
            acc[rt][0] = (f32x4){0.f, 0.f, 0.f, 0.f};                          \
            acc[rt][1] = (f32x4){0.f, 0.f, 0.f, 0.f};                          \
        }                                                                      \
        v8s bf[2][2];                                                          \
        RD(bf[0], 0, BOFF);                                                    \
        RD(bf[1], 1, BOFF);                                                    \
        __builtin_amdgcn_s_setprio(1);                                         \
        _Pragma("unroll")                                                      \
        for (int s = 0; s < 8; ++s) {                                          \
            _Pragma("unroll")                                                  \
            for (int rt = 0; rt < 4; ++rt) {                                   \
                asm("v_mfma_f32_16x16x32_bf16 %0, %1, %2, %0"                  \
                    : "+v"(acc[rt][0]) : "a"(af[rt][s]), "v"(bf[s & 1][0]));   \
                asm("v_mfma_f32_16x16x32_bf16 %0, %1, %2, %0"                  \
                    : "+v"(acc[rt][1]) : "a"(af[rt][s]), "v"(bf[s & 1][1]));   \
            }                                                                  \
            if (s + 2 < 8) RD(bf[s & 1], s + 2, BOFF);                         \
        }                                                                      \
        __builtin_amdgcn_s_setprio(0);                                         \
        _Pragma("unroll")                                                      \
        for (int rt = 0; rt < 4; ++rt)                                         \
            _Pragma("unroll")                                                  \
            for (int r = 0; r < 4; ++r) {                                      \
                const int sl = rt * 4 + r;                                     \
                top3_insert(acc[rt][0][r], t0[sl], t1[sl], t2[sl]);            \
                top3_insert(acc[rt][1][r], t0[sl], t1[sl], t2[sl]);            \
            }                                                                  \
    }

    for (int tt = 0; tt < NT; tt += 2) {
        DO_TILE(0,     16384, tt);       // even tile -> buf0, stage into buf1
        DO_TILE(16384, 0,     tt + 1);   // odd  tile -> buf1, stage into buf0
    }
    #undef DO_TILE
    #undef RD

    // merge across the 16 lo-lanes (same row, different col residues)
    #pragma unroll
    for (int sl = 0; sl < 16; ++sl) {
        #pragma unroll
        for (int step = 1; step < 16; step <<= 1) {
            float b0 = __shfl_xor(t0[sl], step, 64);
            float b1 = __shfl_xor(t1[sl], step, 64);
            float b2 = __shfl_xor(t2[sl], step, 64);
            top3_insert(b0, t0[sl], t1[sl], t2[sl]);
            top3_insert(b1, t0[sl], t1[sl], t2[sl]);
            top3_insert(b2, t0[sl], t1[sl], t2[sl]);
        }
    }
    if (lo == 0) {
        #pragma unroll
        for (int rt = 0; rt < 4; ++rt)
            #pragma unroll
            for (int r = 0; r < 4; ++r) {
                const int row = row0 + wave * 64 + rt * 16 + quad * 4 + r;
                float* p = partial + ((size_t)row * NPART + cs) * 3;
                const int sl = rt * 4 + r;
                p[0] = t0[sl]; p[1] = t1[sl]; p[2] = t2[sl];
            }
    }
}

// 1 thread per row: 12 float4 loads (48 values), 48 inserts.
__global__ __launch_bounds__(256) void merge_kernel(
        const float* __restrict__ partial, float* __restrict__ out) {
    const int row = blockIdx.x * 256 + threadIdx.x;
    if (row >= N1) return;
    const float4* p = (const float4*)(partial + (size_t)row * NPART * 3);
    float t0 = -1e30f, t1 = -1e30f, t2 = -1e30f;
    #pragma unroll
    for (int i = 0; i < 12; ++i) {
        float4 v = p[i];
        top3_insert(v.x, t0, t1, t2);
        top3_insert(v.y, t0, t1, t2);
        top3_insert(v.z, t0, t1, t2);
        top3_insert(v.w, t0, t1, t2);
    }
    out[row] = (t0 + t1 + t2) * (1.0f / 3.0f);
}

extern "C" void kernel_launch(void* const* d_in, const int* in_sizes, int n_in,
                              void* d_out, int out_size, void* d_ws, size_t ws_size,
                              hipStream_t stream) {
    const float* tA = (const float*)d_in[0];
    const float* tB = (const float*)d_in[1];
    float* out = (float*)d_out;

    __hip_bfloat16* An = (__hip_bfloat16*)d_ws;
    __hip_bfloat16* Bn = An + (size_t)N1 * DIM;
    float* partial = (float*)(Bn + (size_t)N2 * DIM);

    normalize_kernel<<<(N1 + N2) / 16, 256, 0, stream>>>(tA, tB, An, Bn);
    gemm_top3_kernel<<<(N1 / BM) * CS, 256, 0, stream>>>(An, Bn, partial);
    merge_kernel<<<N1 / 256, 256, 0, stream>>>(partial, out);
}